// Round 3
// baseline (430.278 us; speedup 1.0000x reference)
//
#include <hip/hip_runtime.h>

// Reference short-circuit:
//   softmax over axis=1 of [S,1] is over a singleton axis == all-ones,
//   so the S x H GEMV (h_s @ h_t) is dead code. Output is
//   c_t[h] = e_t * sum_{s in [w_start, w_end]} h_s[s][h],  window <= 129 rows.
//
// Single fused kernel, NO d_ws usage, no atomics: each of 4 blocks
// redundantly computes the scalar MLP (bit-identical deterministic order),
// then owns a disjoint 256-column strip of the output.

#define HIDDEN   1024
#define N_INTER  256
#define WINDOWF  64.0f

__global__ __launch_bounds__(256) void fused_local_attn(
    const float* __restrict__ hs, const float* __restrict__ ht,
    const float* __restrict__ fc1w, const float* __restrict__ fc1b,
    const float* __restrict__ fc2w, const float* __restrict__ fc2b,
    float* __restrict__ out, int S)
{
    __shared__ float sh_ht[HIDDEN];
    __shared__ float sh_r[N_INTER];
    __shared__ float sh_sc[3];   // e_t, w_start, w_end

    const int tid = threadIdx.x;
    for (int k = tid; k < HIDDEN; k += 256) sh_ht[k] = ht[k];
    __syncthreads();

    // ---- fc1 GEMV: 4 waves x 64 rows, one 64-lane dot per row ----
    const int wave = tid >> 6;
    const int lane = tid & 63;
    for (int j = 0; j < N_INTER / 4; ++j) {
        const int r = wave * (N_INTER / 4) + j;
        const float* __restrict__ row = fc1w + (size_t)r * HIDDEN;
        float d = 0.0f;
        #pragma unroll
        for (int k = 0; k < HIDDEN / 64; ++k)
            d += sh_ht[lane + 64 * k] * row[lane + 64 * k];   // coalesced 256B
        #pragma unroll
        for (int off = 32; off > 0; off >>= 1) d += __shfl_down(d, off);
        if (lane == 0) sh_r[r] = tanhf(d + fc1b[r]) * fc2w[r];
    }
    __syncthreads();

    // ---- scalar epilogue: deterministic serial sum -> identical p_t in
    //      every block (same FP order), so window bounds agree bitwise ----
    if (tid == 0) {
        float z = 0.0f;
        for (int i = 0; i < N_INTER; ++i) z += sh_r[i];
        z += fc2b[0];
        const float sig = 1.0f / (1.0f + expf(-z));
        const float p_t = (float)S * sig;
        float wsf = ceilf(p_t - WINDOWF);  if (wsf < 0.0f) wsf = 0.0f;
        float wef = floorf(p_t + WINDOWF);
        const float smax = (float)(S - 1); if (wef > smax) wef = smax;
        // e_t uses S (faithful reference quirk); 2*STD_SQUARED = 2048
        sh_sc[0] = expf(((float)S - p_t) * (1.0f / 2048.0f));
        sh_sc[1] = wsf; sh_sc[2] = wef;
    }
    __syncthreads();

    const float e_t = sh_sc[0];
    const int wstart = (int)sh_sc[1];
    const int wend   = (int)sh_sc[2];

    // ---- window column-sum: block owns columns [256*bx, 256*bx+255] ----
    const int col = (int)blockIdx.x * 256 + tid;   // coalesced rows of 1KB
    float acc = 0.0f;
    for (int r = wstart; r <= wend; ++r)           // <= 129 iterations
        acc += hs[(size_t)r * HIDDEN + col];

    out[col] = e_t * acc;                          // every column written once
}

extern "C" void kernel_launch(void* const* d_in, const int* in_sizes, int n_in,
                              void* d_out, int out_size, void* d_ws, size_t ws_size,
                              hipStream_t stream) {
    const float* hs   = (const float*)d_in[0];  // [S, 1024]
    const float* ht   = (const float*)d_in[1];  // [1, 1024]
    const float* fc1w = (const float*)d_in[2];  // [256, 1024]
    const float* fc1b = (const float*)d_in[3];  // [256]
    const float* fc2w = (const float*)d_in[4];  // [1, 256]
    const float* fc2b = (const float*)d_in[5];  // [1]
    const int S = in_sizes[0] / HIDDEN;

    fused_local_attn<<<HIDDEN / 256, 256, 0, stream>>>(
        hs, ht, fc1w, fc1b, fc2w, fc2b, (float*)d_out, S);
}